// Round 1
// baseline (164.620 us; speedup 1.0000x reference)
//
#include <hip/hip_runtime.h>
#include <math.h>

#define IT 3
#define ROWS 144
#define NCOLS 576
#define ROW_DEG 6

// Soft 4-level quantizer: softmax(-(x-qk)^2 / (2*eta^2+1e-12)) dot qk.
// Max-subtraction is required: raw logits reach ~-200 -> expf underflow -> 0/0.
__device__ __forceinline__ float quantize4(float x, float inv2e,
                                           float q0, float q1, float q2, float q3) {
    float d0 = x - q0, d1 = x - q1, d2 = x - q2, d3 = x - q3;
    float l0 = -d0 * d0 * inv2e;
    float l1 = -d1 * d1 * inv2e;
    float l2 = -d2 * d2 * inv2e;
    float l3 = -d3 * d3 * inv2e;
    float mx = fmaxf(fmaxf(l0, l1), fmaxf(l2, l3));
    float w0 = expf(l0 - mx), w1 = expf(l1 - mx), w2 = expf(l2 - mx), w3 = expf(l3 - mx);
    float s = w0 + w1 + w2 + w3;
    return (w0 * q0 + w1 * q1 + w2 * q2 + w3 * q3) / s;
}

__device__ __forceinline__ float signf(float x) {
    return (x > 0.0f) ? 1.0f : ((x < 0.0f) ? -1.0f : 0.0f);
}

// Extract the 6 column indices of each check row from dense H (scan ascending,
// so edges are ordered by column -> argmin tie-break matches jax top_k).
__global__ void extract_cols_kernel(const float* __restrict__ H, int* __restrict__ cols) {
    int row = blockIdx.x * blockDim.x + threadIdx.x;
    if (row >= ROWS) return;
    int k = 0;
    for (int j = 0; j < NCOLS; ++j) {
        if (H[row * NCOLS + j] != 0.0f) {
            if (k < ROW_DEG) cols[row * ROW_DEG + k] = j;
            ++k;
        }
    }
}

// One block per batch item; one thread per check row (144 active of 192).
__global__ __launch_bounds__(192) void decode_kernel(
    const float* __restrict__ r, const int* __restrict__ cols,
    const float* __restrict__ alpha, const float* __restrict__ beta,
    const float* __restrict__ eta, const float* __restrict__ qk,
    float* __restrict__ out)
{
    __shared__ float s_r[NCOLS];
    __shared__ float s_sumE[NCOLS];

    const int b = blockIdx.x;
    const float* rb = r + (size_t)b * NCOLS;
    for (int j = threadIdx.x; j < NCOLS; j += blockDim.x) s_r[j] = rb[j];

    const float q0 = qk[0], q1 = qk[1], q2 = qk[2], q3 = qk[3];
    const int row = threadIdx.x;
    const bool active = row < ROWS;

    int   c[ROW_DEG];
    float m[ROW_DEG];
    float E[ROW_DEG];

    __syncthreads();
    if (active) {
        for (int e = 0; e < ROW_DEG; ++e) {
            c[e] = cols[row * ROW_DEG + e];
            m[e] = s_r[c[e]];
        }
    }

    for (int t = 0; t < IT; ++t) {
        const float al = alpha[t], be = beta[t], et = eta[t];
        const float inv2e = 1.0f / (2.0f * et * et + 1e-12f);

        __syncthreads();  // previous iter's s_sumE reads must finish before re-zero
        for (int j = threadIdx.x; j < NCOLS; j += blockDim.x) s_sumE[j] = 0.0f;
        __syncthreads();

        if (active) {
            // top-2 min of |m| + index of min1 (first occurrence), sign product
            float min1 = INFINITY, min2 = INFINITY;
            int idx = -1;
            float sp = 1.0f;
            for (int e = 0; e < ROW_DEG; ++e) {
                float a = fabsf(m[e]);
                sp *= signf(m[e]);
                if (a < min1) { min2 = min1; min1 = a; idx = e; }
                else if (a < min2) { min2 = a; }
            }
            for (int e = 0; e < ROW_DEG; ++e) {
                float eabs = (e == idx) ? min2 : min1;
                float v = al * sp * signf(m[e]) * fmaxf(0.0f, eabs - be);
                v = quantize4(v, inv2e, q0, q1, q2, q3);
                E[e] = v;
                atomicAdd(&s_sumE[c[e]], v);  // avg col degree 1.5 -> no contention
            }
        }
        __syncthreads();

        if (t < IT - 1 && active) {
            for (int e = 0; e < ROW_DEG; ++e) {
                float v = s_r[c[e]] + s_sumE[c[e]] - E[e];
                m[e] = quantize4(v, inv2e, q0, q1, q2, q3);
            }
        }
    }

    // out = r + colsum(E_final); s_sumE holds exactly that after the last iter.
    float* ob = out + (size_t)b * NCOLS;
    for (int j = threadIdx.x; j < NCOLS; j += blockDim.x) ob[j] = s_r[j] + s_sumE[j];
}

extern "C" void kernel_launch(void* const* d_in, const int* in_sizes, int n_in,
                              void* d_out, int out_size, void* d_ws, size_t ws_size,
                              hipStream_t stream) {
    const float* r     = (const float*)d_in[0];
    const float* H     = (const float*)d_in[1];
    const float* alpha = (const float*)d_in[2];
    const float* beta  = (const float*)d_in[3];
    const float* eta   = (const float*)d_in[4];
    const float* qk    = (const float*)d_in[5];
    float* out = (float*)d_out;

    int* cols = (int*)d_ws;  // ROWS*ROW_DEG ints = 3456 B of scratch
    const int batch = in_sizes[0] / NCOLS;

    hipLaunchKernelGGL(extract_cols_kernel, dim3((ROWS + 63) / 64), dim3(64), 0, stream,
                       H, cols);
    hipLaunchKernelGGL(decode_kernel, dim3(batch), dim3(192), 0, stream,
                       r, cols, alpha, beta, eta, qk, out);
}

// Round 2
// 80.206 us; speedup vs baseline: 2.0525x; 2.0525x over previous
//
#include <hip/hip_runtime.h>
#include <math.h>

#define IT 3
#define ROWS 144
#define NCOLS 576
#define ROW_DEG 6

// Soft 4-level quantizer: softmax(-(x-qk)^2 / (2*eta^2+1e-12)) dot qk.
// Max-subtraction required: raw logits reach ~-200 -> exp underflow -> 0/0.
// __expf (v_exp_f32) is fine: absmax headroom is ~6x the observed error.
__device__ __forceinline__ float quantize4(float x, float inv2e,
                                           float q0, float q1, float q2, float q3) {
    float d0 = x - q0, d1 = x - q1, d2 = x - q2, d3 = x - q3;
    float l0 = -d0 * d0 * inv2e;
    float l1 = -d1 * d1 * inv2e;
    float l2 = -d2 * d2 * inv2e;
    float l3 = -d3 * d3 * inv2e;
    float mx = fmaxf(fmaxf(l0, l1), fmaxf(l2, l3));
    float w0 = __expf(l0 - mx), w1 = __expf(l1 - mx);
    float w2 = __expf(l2 - mx), w3 = __expf(l3 - mx);
    float s = w0 + w1 + w2 + w3;
    return (w0 * q0 + w1 * q1 + w2 * q2 + w3 * q3) / s;
}

__device__ __forceinline__ float signf(float x) {
    return (x > 0.0f) ? 1.0f : ((x < 0.0f) ? -1.0f : 0.0f);
}

// One wave per row: 9 coalesced 64-lane loads cover 576 columns; ballot+popc
// prefix compacts nonzero column indices in ascending order (matches jax
// top_k first-occurrence tie-break downstream).
__global__ __launch_bounds__(64) void extract_cols_kernel(
    const float* __restrict__ H, int* __restrict__ cols)
{
    const int row  = blockIdx.x;
    const int lane = threadIdx.x;
    int base = 0;
    for (int i = 0; i < NCOLS / 64; ++i) {
        int col = i * 64 + lane;
        bool nz = H[row * NCOLS + col] != 0.0f;
        unsigned long long mask = __ballot(nz);
        if (nz) {
            int rank = base + __popcll(mask & ((1ull << lane) - 1ull));
            if (rank < ROW_DEG) cols[row * ROW_DEG + rank] = col;
        }
        base += __popcll(mask);
    }
}

// One block per batch item; one thread per check row (144 active of 192).
__global__ __launch_bounds__(192) void decode_kernel(
    const float* __restrict__ r, const int* __restrict__ cols,
    const float* __restrict__ alpha, const float* __restrict__ beta,
    const float* __restrict__ eta, const float* __restrict__ qk,
    float* __restrict__ out)
{
    __shared__ float s_r[NCOLS];
    __shared__ float s_sumE[NCOLS];

    const int b = blockIdx.x;
    const float* rb = r + (size_t)b * NCOLS;
    for (int j = threadIdx.x; j < NCOLS; j += blockDim.x) s_r[j] = rb[j];

    // Hoist all scalar params out of the iteration loop.
    const float q0 = qk[0], q1 = qk[1], q2 = qk[2], q3 = qk[3];
    float al[IT], be[IT], i2e[IT];
    for (int t = 0; t < IT; ++t) {
        al[t] = alpha[t];
        be[t] = beta[t];
        float et = eta[t];
        i2e[t] = 1.0f / (2.0f * et * et + 1e-12f);
    }

    const int row = threadIdx.x;
    const bool active = row < ROWS;

    int   c[ROW_DEG];
    float m[ROW_DEG];
    float E[ROW_DEG];

    __syncthreads();
    if (active) {
        for (int e = 0; e < ROW_DEG; ++e) {
            c[e] = cols[row * ROW_DEG + e];
            m[e] = s_r[c[e]];
        }
    }

    for (int t = 0; t < IT; ++t) {
        const float inv2e = i2e[t];

        __syncthreads();  // previous iter's s_sumE reads must finish before re-zero
        for (int j = threadIdx.x; j < NCOLS; j += blockDim.x) s_sumE[j] = 0.0f;
        __syncthreads();

        if (active) {
            // top-2 min of |m| + index of min1 (first occurrence), sign product
            float min1 = INFINITY, min2 = INFINITY;
            int idx = -1;
            float sp = 1.0f;
            for (int e = 0; e < ROW_DEG; ++e) {
                float a = fabsf(m[e]);
                sp *= signf(m[e]);
                if (a < min1) { min2 = min1; min1 = a; idx = e; }
                else if (a < min2) { min2 = a; }
            }
            for (int e = 0; e < ROW_DEG; ++e) {
                float eabs = (e == idx) ? min2 : min1;
                float v = al[t] * sp * signf(m[e]) * fmaxf(0.0f, eabs - be[t]);
                v = quantize4(v, inv2e, q0, q1, q2, q3);
                E[e] = v;
                atomicAdd(&s_sumE[c[e]], v);  // avg col degree 1.5 -> no contention
            }
        }
        __syncthreads();

        if (t < IT - 1 && active) {
            for (int e = 0; e < ROW_DEG; ++e) {
                float v = s_r[c[e]] + s_sumE[c[e]] - E[e];
                m[e] = quantize4(v, inv2e, q0, q1, q2, q3);
            }
        }
    }

    // out = r + colsum(E_final); s_sumE holds exactly that after the last iter.
    float* ob = out + (size_t)b * NCOLS;
    for (int j = threadIdx.x; j < NCOLS; j += blockDim.x) ob[j] = s_r[j] + s_sumE[j];
}

extern "C" void kernel_launch(void* const* d_in, const int* in_sizes, int n_in,
                              void* d_out, int out_size, void* d_ws, size_t ws_size,
                              hipStream_t stream) {
    const float* r     = (const float*)d_in[0];
    const float* H     = (const float*)d_in[1];
    const float* alpha = (const float*)d_in[2];
    const float* beta  = (const float*)d_in[3];
    const float* eta   = (const float*)d_in[4];
    const float* qk    = (const float*)d_in[5];
    float* out = (float*)d_out;

    int* cols = (int*)d_ws;  // ROWS*ROW_DEG ints = 3456 B of scratch
    const int batch = in_sizes[0] / NCOLS;

    hipLaunchKernelGGL(extract_cols_kernel, dim3(ROWS), dim3(64), 0, stream,
                       H, cols);
    hipLaunchKernelGGL(decode_kernel, dim3(batch), dim3(192), 0, stream,
                       r, cols, alpha, beta, eta, qk, out);
}